// Round 1
// baseline (2333.679 us; speedup 1.0000x reference)
//
#include <hip/hip_runtime.h>
#include <cstdint>
#include <cstddef>

#define B_  4
#define S_  2048
#define D_  1024
#define DK_ 128

// ---------------------------------------------------------------------------
// lengths[b] = number of non-padded positions (mask rows are 0..0 1..1).
// Storage of the bool mask may be 1-byte or int32 depending on harness
// marshalling; byte S_-1 (=2047) is element [0][2047] under 1-byte layout,
// which is guaranteed True (lengths <= 2047), but is a zero high byte under
// int32 layout -> use it as a discriminator.
// ---------------------------------------------------------------------------
__global__ void lengths_kernel(const uint8_t* __restrict__ mask,
                               int* __restrict__ lengths) {
    int b = blockIdx.x;
    bool is_i32 = (mask[S_ - 1] == 0);
    __shared__ int cnt[256];
    int t = threadIdx.x;
    int c = 0;
    for (int i = t; i < S_; i += 256) {
        int val;
        if (is_i32) val = ((const int*)mask)[b * S_ + i];
        else        val = mask[b * S_ + i];
        c += (val == 0) ? 1 : 0;
    }
    cnt[t] = c;
    __syncthreads();
    for (int s = 128; s > 0; s >>= 1) {
        if (t < s) cnt[t] += cnt[t + s];
        __syncthreads();
    }
    if (t == 0) lengths[b] = cnt[0];
}

// ---------------------------------------------------------------------------
// C[M,N] = A[M,K] @ W[K,N] + bias[N]   (fp32, tiled)
// BM=64 BN=64 BK=16, 256 threads, 4x4 microtile per thread.
// ---------------------------------------------------------------------------
#define BM 64
#define BN 64
#define BK 16

__global__ __launch_bounds__(256) void gemm_bias(
    const float* __restrict__ A, const float* __restrict__ W,
    const float* __restrict__ bias, float* __restrict__ C,
    int M, int N, int K)
{
    __shared__ float As[BK][BM + 4];   // stride 68 floats = 272B, 16B-aligned rows
    __shared__ float Ws[BK][BN];

    const int t  = threadIdx.x;
    const int m0 = blockIdx.y * BM;
    const int n0 = blockIdx.x * BN;
    const int tx = t & 15;
    const int ty = t >> 4;

    // A-load: thread -> row t>>2 (0..63), k-offset (t&3)*4
    const int ar = t >> 2;
    const int ak = (t & 3) * 4;
    // W-load: thread -> k-row t>>4 (0..15), n-offset (t&15)*4
    const int wr = t >> 4;
    const int wc = (t & 15) * 4;

    float acc[4][4] = {};

    for (int k0 = 0; k0 < K; k0 += BK) {
        float4 av = *(const float4*)&A[(size_t)(m0 + ar) * K + k0 + ak];
        float4 wv = *(const float4*)&W[(size_t)(k0 + wr) * N + n0 + wc];
        __syncthreads();
        As[ak + 0][ar] = av.x;
        As[ak + 1][ar] = av.y;
        As[ak + 2][ar] = av.z;
        As[ak + 3][ar] = av.w;
        *(float4*)&Ws[wr][wc] = wv;
        __syncthreads();
#pragma unroll
        for (int kk = 0; kk < BK; ++kk) {
            float4 a4 = *(const float4*)&As[kk][ty * 4];
            float4 b4 = *(const float4*)&Ws[kk][tx * 4];
            float a_[4] = {a4.x, a4.y, a4.z, a4.w};
            float b_[4] = {b4.x, b4.y, b4.z, b4.w};
#pragma unroll
            for (int i = 0; i < 4; ++i)
#pragma unroll
                for (int j = 0; j < 4; ++j)
                    acc[i][j] += a_[i] * b_[j];
        }
    }

    float4 bs = *(const float4*)&bias[n0 + tx * 4];
#pragma unroll
    for (int i = 0; i < 4; ++i) {
        int row = m0 + ty * 4 + i;
        float4 o;
        o.x = acc[i][0] + bs.x;
        o.y = acc[i][1] + bs.y;
        o.z = acc[i][2] + bs.z;
        o.w = acc[i][3] + bs.w;
        *(float4*)&C[(size_t)row * N + n0 + tx * 4] = o;
    }
}

// ---------------------------------------------------------------------------
// vsum[b][d] = sum_s v[b][s][d]   (atomicAdd of per-block partials; vsum
// must be zeroed before launch)
// ---------------------------------------------------------------------------
__global__ void vsum_kernel(const float* __restrict__ v, float* __restrict__ vsum) {
    const int d = blockIdx.x * 256 + threadIdx.x;
    const int b = blockIdx.y;
    const int chunk = blockIdx.z;
    const int ROWS = S_ / 8;
    const int r0 = chunk * ROWS;
    float s = 0.f;
    for (int r = 0; r < ROWS; ++r)
        s += v[((size_t)(b * S_ + r0 + r)) * D_ + d];
    atomicAdd(&vsum[b * D_ + d], s);
}

// ---------------------------------------------------------------------------
// Flash attention, fp32. Grid (S/16, B), 256 threads.
// Row group: rloc = t>>4 (16 rows), lane16 = t&15.
// Each thread owns row rloc, float4-columns c4 = lane16 + jj*16 (jj=0..15).
// Valid rows (q < len): causal softmax over k in [0,q].
// Padded rows (q >= len): out = vsum / S.
// ---------------------------------------------------------------------------
__global__ __launch_bounds__(256) void flash_attn(
    const float* __restrict__ q, const float* __restrict__ k,
    const float* __restrict__ v, const float* __restrict__ vsum,
    const int* __restrict__ lengths, float* __restrict__ out)
{
    const int b      = blockIdx.y;
    const int r0     = blockIdx.x * 16;
    const int t      = threadIdx.x;
    const int lane16 = t & 15;
    const int rloc   = t >> 4;
    const int rglob  = r0 + rloc;
    const int len    = lengths[b];

    if (r0 >= len) {  // whole tile padded: uniform attention = mean of v
        const float inv = 1.0f / (float)S_;
        const float4* vs4 = (const float4*)&vsum[b * D_];
        float4* o4 = (float4*)&out[((size_t)(b * S_ + rglob)) * D_];
#pragma unroll
        for (int jj = 0; jj < 16; ++jj) {
            float4 vv = vs4[lane16 + jj * 16];
            o4[lane16 + jj * 16] = make_float4(vv.x * inv, vv.y * inv, vv.z * inv, vv.w * inv);
        }
        return;
    }

    __shared__ float qs[16][DK_ + 4];
    __shared__ float ks[32][DK_ + 4];
    __shared__ float ps[16][32];

    const float scale = 0.08838834764831845f;  // 1/sqrt(128)
    for (int idx = t; idx < 512; idx += 256) { // 16 rows x 32 float4
        int rr = idx >> 5, c4 = idx & 31;
        float4 qv = *(const float4*)&q[((size_t)(b * S_ + r0 + rr)) * DK_ + c4 * 4];
        qv.x *= scale; qv.y *= scale; qv.z *= scale; qv.w *= scale;
        *(float4*)&qs[rr][c4 * 4] = qv;
    }

    float4 acc[16];
#pragma unroll
    for (int jj = 0; jj < 16; ++jj) acc[jj] = make_float4(0.f, 0.f, 0.f, 0.f);
    float m_r = -3.0e38f, l_r = 0.f;

    const int kmax = min(r0 + 15, len - 1);
    for (int kb = 0; kb <= kmax; kb += 32) {
        // stage k chunk (32 rows x 128)
        for (int idx = t; idx < 1024; idx += 256) { // 32 rows x 32 float4
            int rr = idx >> 5, c4 = idx & 31;
            float4 kv = *(const float4*)&k[((size_t)(b * S_ + kb + rr)) * DK_ + c4 * 4];
            *(float4*)&ks[rr][c4 * 4] = kv;
        }
        __syncthreads();  // B: ks/qs ready; also guards ps reuse from prev PV

        // scores: this thread covers columns lane16 and lane16+16
        float s0 = 0.f, s1 = 0.f;
#pragma unroll 8
        for (int d4 = 0; d4 < 32; ++d4) {
            float4 qv = *(const float4*)&qs[rloc][d4 * 4];
            float4 k0 = *(const float4*)&ks[lane16][d4 * 4];
            float4 k1 = *(const float4*)&ks[lane16 + 16][d4 * 4];
            s0 += qv.x * k0.x + qv.y * k0.y + qv.z * k0.z + qv.w * k0.w;
            s1 += qv.x * k1.x + qv.y * k1.y + qv.z * k1.z + qv.w * k1.w;
        }
        if (kb + lane16 > rglob)      s0 = -3.0e38f;
        if (kb + lane16 + 16 > rglob) s1 = -3.0e38f;

        float cmax = fmaxf(s0, s1);
#pragma unroll
        for (int off = 1; off < 16; off <<= 1)
            cmax = fmaxf(cmax, __shfl_xor(cmax, off, 16));
        float m_new = fmaxf(m_r, cmax);
        float p0 = __expf(s0 - m_new);
        float p1 = __expf(s1 - m_new);
        float rs = p0 + p1;
#pragma unroll
        for (int off = 1; off < 16; off <<= 1)
            rs += __shfl_xor(rs, off, 16);
        float sc_old = __expf(m_r - m_new);
        l_r = l_r * sc_old + rs;
        m_r = m_new;
        ps[rloc][lane16]      = p0;
        ps[rloc][lane16 + 16] = p1;
#pragma unroll
        for (int jj = 0; jj < 16; ++jj) {
            acc[jj].x *= sc_old; acc[jj].y *= sc_old;
            acc[jj].z *= sc_old; acc[jj].w *= sc_old;
        }
        __syncthreads();  // C: ps visible to all; scores phase done

        // PV accumulate
        const int klim = min(32, kmax - kb + 1);
        for (int kk = 0; kk < klim; ++kk) {
            float pv = ps[rloc][kk];
            const float4* vrow = (const float4*)&v[((size_t)(b * S_ + kb + kk)) * D_];
#pragma unroll
            for (int jj = 0; jj < 16; ++jj) {
                float4 vv = vrow[lane16 + jj * 16];
                acc[jj].x += pv * vv.x; acc[jj].y += pv * vv.y;
                acc[jj].z += pv * vv.z; acc[jj].w += pv * vv.w;
            }
        }
        __syncthreads();  // ps/ks safe to overwrite next iteration
    }

    float4* o4 = (float4*)&out[((size_t)(b * S_ + rglob)) * D_];
    if (rglob < len) {
        const float inv = 1.0f / l_r;
#pragma unroll
        for (int jj = 0; jj < 16; ++jj)
            o4[lane16 + jj * 16] = make_float4(acc[jj].x * inv, acc[jj].y * inv,
                                               acc[jj].z * inv, acc[jj].w * inv);
    } else {  // padded row inside a mixed tile
        const float inv = 1.0f / (float)S_;
        const float4* vs4 = (const float4*)&vsum[b * D_];
#pragma unroll
        for (int jj = 0; jj < 16; ++jj) {
            float4 vv = vs4[lane16 + jj * 16];
            o4[lane16 + jj * 16] = make_float4(vv.x * inv, vv.y * inv, vv.z * inv, vv.w * inv);
        }
    }
}

// ---------------------------------------------------------------------------
extern "C" void kernel_launch(void* const* d_in, const int* in_sizes, int n_in,
                              void* d_out, int out_size, void* d_ws, size_t ws_size,
                              hipStream_t stream) {
    const float*   x    = (const float*)d_in[0];
    const uint8_t* mask = (const uint8_t*)d_in[1];
    const float*   Wq   = (const float*)d_in[2];
    const float*   bq   = (const float*)d_in[3];
    const float*   Wk   = (const float*)d_in[4];
    const float*   bk   = (const float*)d_in[5];
    const float*   Wv   = (const float*)d_in[6];
    const float*   bv   = (const float*)d_in[7];
    float* out = (float*)d_out;

    float* ws   = (float*)d_ws;
    float* q    = ws;                                   // 8192*128
    float* k    = ws + (size_t)8192 * 128;              // 8192*128
    float* v    = ws + (size_t)8192 * 128 * 2;          // 8192*1024
    float* vsum = v + (size_t)8192 * 1024;              // 4096
    int* lengths = (int*)(vsum + 4096);                 // 4

    hipMemsetAsync(vsum, 0, 4096 * sizeof(float), stream);
    lengths_kernel<<<dim3(B_), dim3(256), 0, stream>>>(mask, lengths);

    gemm_bias<<<dim3(DK_ / BN, (B_ * S_) / BM), 256, 0, stream>>>(x, Wq, bq, q, B_ * S_, DK_, D_);
    gemm_bias<<<dim3(DK_ / BN, (B_ * S_) / BM), 256, 0, stream>>>(x, Wk, bk, k, B_ * S_, DK_, D_);
    gemm_bias<<<dim3(D_ / BN, (B_ * S_) / BM), 256, 0, stream>>>(x, Wv, bv, v, B_ * S_, D_, D_);

    vsum_kernel<<<dim3(D_ / 256, B_, 8), 256, 0, stream>>>(v, vsum);

    flash_attn<<<dim3(S_ / 16, B_), 256, 0, stream>>>(q, k, v, vsum, lengths, out);
}

// Round 2
// 1659.078 us; speedup vs baseline: 1.4066x; 1.4066x over previous
//
#include <hip/hip_runtime.h>
#include <cstdint>
#include <cstddef>

#define B_  4
#define S_  2048
#define D_  1024
#define DK_ 128

// ---------------------------------------------------------------------------
// lengths[b] = number of non-padded positions (mask rows are 0..0 1..1).
// Storage of the bool mask may be 1-byte or int32 depending on harness
// marshalling; byte S_-1 (=2047) is element [0][2047] under 1-byte layout,
// which is guaranteed True (lengths <= 2047), but is a zero high byte under
// int32 layout -> use it as a discriminator.
// ---------------------------------------------------------------------------
__global__ void lengths_kernel(const uint8_t* __restrict__ mask,
                               int* __restrict__ lengths) {
    int b = blockIdx.x;
    bool is_i32 = (mask[S_ - 1] == 0);
    __shared__ int cnt[256];
    int t = threadIdx.x;
    int c = 0;
    for (int i = t; i < S_; i += 256) {
        int val;
        if (is_i32) val = ((const int*)mask)[b * S_ + i];
        else        val = mask[b * S_ + i];
        c += (val == 0) ? 1 : 0;
    }
    cnt[t] = c;
    __syncthreads();
    for (int s = 128; s > 0; s >>= 1) {
        if (t < s) cnt[t] += cnt[t + s];
        __syncthreads();
    }
    if (t == 0) lengths[b] = cnt[0];
}

// ---------------------------------------------------------------------------
// C[M,N] = A[M,K] @ W[K,N] + bias[N]   (fp32, tiled)
// BM=64 BN=64 BK=16, 256 threads, 4x4 microtile per thread.
// ---------------------------------------------------------------------------
#define BM 64
#define BN 64
#define BK 16

__global__ __launch_bounds__(256) void gemm_bias(
    const float* __restrict__ A, const float* __restrict__ W,
    const float* __restrict__ bias, float* __restrict__ C,
    int M, int N, int K)
{
    __shared__ float As[BK][BM + 4];
    __shared__ float Ws[BK][BN];

    const int t  = threadIdx.x;
    const int m0 = blockIdx.y * BM;
    const int n0 = blockIdx.x * BN;
    const int tx = t & 15;
    const int ty = t >> 4;

    const int ar = t >> 2;
    const int ak = (t & 3) * 4;
    const int wr = t >> 4;
    const int wc = (t & 15) * 4;

    float acc[4][4] = {};

    for (int k0 = 0; k0 < K; k0 += BK) {
        float4 av = *(const float4*)&A[(size_t)(m0 + ar) * K + k0 + ak];
        float4 wv = *(const float4*)&W[(size_t)(k0 + wr) * N + n0 + wc];
        __syncthreads();
        As[ak + 0][ar] = av.x;
        As[ak + 1][ar] = av.y;
        As[ak + 2][ar] = av.z;
        As[ak + 3][ar] = av.w;
        *(float4*)&Ws[wr][wc] = wv;
        __syncthreads();
#pragma unroll
        for (int kk = 0; kk < BK; ++kk) {
            float4 a4 = *(const float4*)&As[kk][ty * 4];
            float4 b4 = *(const float4*)&Ws[kk][tx * 4];
            float a_[4] = {a4.x, a4.y, a4.z, a4.w};
            float b_[4] = {b4.x, b4.y, b4.z, b4.w};
#pragma unroll
            for (int i = 0; i < 4; ++i)
#pragma unroll
                for (int j = 0; j < 4; ++j)
                    acc[i][j] += a_[i] * b_[j];
        }
    }

    float4 bs = *(const float4*)&bias[n0 + tx * 4];
#pragma unroll
    for (int i = 0; i < 4; ++i) {
        int row = m0 + ty * 4 + i;
        float4 o;
        o.x = acc[i][0] + bs.x;
        o.y = acc[i][1] + bs.y;
        o.z = acc[i][2] + bs.z;
        o.w = acc[i][3] + bs.w;
        *(float4*)&C[(size_t)row * N + n0 + tx * 4] = o;
    }
}

// ---------------------------------------------------------------------------
// vsum[b][d] = sum_s v[b][s][d]
// ---------------------------------------------------------------------------
__global__ void vsum_kernel(const float* __restrict__ v, float* __restrict__ vsum) {
    const int d = blockIdx.x * 256 + threadIdx.x;
    const int b = blockIdx.y;
    const int chunk = blockIdx.z;
    const int ROWS = S_ / 8;
    const int r0 = chunk * ROWS;
    float s = 0.f;
    for (int r = 0; r < ROWS; ++r)
        s += v[((size_t)(b * S_ + r0 + r)) * D_ + d];
    atomicAdd(&vsum[b * D_ + d], s);
}

// ---------------------------------------------------------------------------
// Flash attention, fp32, D-SLICED for occupancy.
// Grid (S/16, B, 4): z = which 256-col slice of D this block produces.
// 256 threads: rloc = t>>4 (16 q-rows), lane16 = t&15.
// Each block computes the full QK^T + online softmax for its 16 q-rows
// (duplicated across the 4 slices -- QK is ~11% of FLOPs), but accumulates
// PV and writes output only for its 256-column slice (4 float4 per thread).
// Valid rows (q < len): causal softmax over k in [0,q].
// Padded rows (q >= len): out = vsum / S.
// ---------------------------------------------------------------------------
#define NSLICE 4
#define SLICE_F4 64   // 256 cols = 64 float4 per slice

__global__ __launch_bounds__(256) void flash_attn(
    const float* __restrict__ q, const float* __restrict__ k,
    const float* __restrict__ v, const float* __restrict__ vsum,
    const int* __restrict__ lengths, float* __restrict__ out)
{
    const int b      = blockIdx.y;
    const int r0     = blockIdx.x * 16;
    const int slice  = blockIdx.z;
    const int t      = threadIdx.x;
    const int lane16 = t & 15;
    const int rloc   = t >> 4;
    const int rglob  = r0 + rloc;
    const int len    = lengths[b];
    const int c4base = slice * SLICE_F4 + lane16;  // float4 index into D

    if (r0 >= len) {  // whole tile padded: uniform attention = mean of v
        const float inv = 1.0f / (float)S_;
        const float4* vs4 = (const float4*)&vsum[b * D_];
        float4* o4 = (float4*)&out[((size_t)(b * S_ + rglob)) * D_];
#pragma unroll
        for (int jj = 0; jj < 4; ++jj) {
            int c4 = c4base + jj * 16;
            float4 vv = vs4[c4];
            o4[c4] = make_float4(vv.x * inv, vv.y * inv, vv.z * inv, vv.w * inv);
        }
        return;
    }

    __shared__ float qs[16][DK_ + 4];
    __shared__ float ks[32][DK_ + 4];
    __shared__ float ps[16][32];

    const float scale = 0.08838834764831845f;  // 1/sqrt(128)
    for (int idx = t; idx < 512; idx += 256) { // 16 rows x 32 float4
        int rr = idx >> 5, c4 = idx & 31;
        float4 qv = *(const float4*)&q[((size_t)(b * S_ + r0 + rr)) * DK_ + c4 * 4];
        qv.x *= scale; qv.y *= scale; qv.z *= scale; qv.w *= scale;
        *(float4*)&qs[rr][c4 * 4] = qv;
    }

    float4 acc[4];
#pragma unroll
    for (int jj = 0; jj < 4; ++jj) acc[jj] = make_float4(0.f, 0.f, 0.f, 0.f);
    float m_r = -3.0e38f, l_r = 0.f;

    const int kmax = min(r0 + 15, len - 1);
    for (int kb = 0; kb <= kmax; kb += 32) {
        // stage k chunk (32 rows x 128)
        for (int idx = t; idx < 1024; idx += 256) { // 32 rows x 32 float4
            int rr = idx >> 5, c4 = idx & 31;
            float4 kv = *(const float4*)&k[((size_t)(b * S_ + kb + rr)) * DK_ + c4 * 4];
            *(float4*)&ks[rr][c4 * 4] = kv;
        }
        __syncthreads();  // ks/qs ready; also guards ps reuse from prev PV

        // scores: this thread covers key columns lane16 and lane16+16
        float s0 = 0.f, s1 = 0.f;
#pragma unroll 8
        for (int d4 = 0; d4 < 32; ++d4) {
            float4 qv = *(const float4*)&qs[rloc][d4 * 4];
            float4 k0 = *(const float4*)&ks[lane16][d4 * 4];
            float4 k1 = *(const float4*)&ks[lane16 + 16][d4 * 4];
            s0 += qv.x * k0.x + qv.y * k0.y + qv.z * k0.z + qv.w * k0.w;
            s1 += qv.x * k1.x + qv.y * k1.y + qv.z * k1.z + qv.w * k1.w;
        }
        if (kb + lane16 > rglob)      s0 = -3.0e38f;
        if (kb + lane16 + 16 > rglob) s1 = -3.0e38f;

        float cmax = fmaxf(s0, s1);
#pragma unroll
        for (int off = 1; off < 16; off <<= 1)
            cmax = fmaxf(cmax, __shfl_xor(cmax, off, 16));
        float m_new = fmaxf(m_r, cmax);
        float p0 = __expf(s0 - m_new);
        float p1 = __expf(s1 - m_new);
        float rs = p0 + p1;
#pragma unroll
        for (int off = 1; off < 16; off <<= 1)
            rs += __shfl_xor(rs, off, 16);
        float sc_old = __expf(m_r - m_new);
        l_r = l_r * sc_old + rs;
        m_r = m_new;
        ps[rloc][lane16]      = p0;
        ps[rloc][lane16 + 16] = p1;
#pragma unroll
        for (int jj = 0; jj < 4; ++jj) {
            acc[jj].x *= sc_old; acc[jj].y *= sc_old;
            acc[jj].z *= sc_old; acc[jj].w *= sc_old;
        }
        __syncthreads();  // ps visible

        // PV accumulate over this block's 256-col slice
        const int klim = min(32, kmax - kb + 1);
        if (klim == 32) {
#pragma unroll 4
            for (int kk = 0; kk < 32; ++kk) {
                float pv = ps[rloc][kk];
                const float4* vrow = (const float4*)&v[((size_t)(b * S_ + kb + kk)) * D_];
#pragma unroll
                for (int jj = 0; jj < 4; ++jj) {
                    float4 vv = vrow[c4base + jj * 16];
                    acc[jj].x += pv * vv.x; acc[jj].y += pv * vv.y;
                    acc[jj].z += pv * vv.z; acc[jj].w += pv * vv.w;
                }
            }
        } else {
            for (int kk = 0; kk < klim; ++kk) {
                float pv = ps[rloc][kk];
                const float4* vrow = (const float4*)&v[((size_t)(b * S_ + kb + kk)) * D_];
#pragma unroll
                for (int jj = 0; jj < 4; ++jj) {
                    float4 vv = vrow[c4base + jj * 16];
                    acc[jj].x += pv * vv.x; acc[jj].y += pv * vv.y;
                    acc[jj].z += pv * vv.z; acc[jj].w += pv * vv.w;
                }
            }
        }
        __syncthreads();  // ps/ks safe to overwrite next iteration
    }

    float4* o4 = (float4*)&out[((size_t)(b * S_ + rglob)) * D_];
    if (rglob < len) {
        const float inv = 1.0f / l_r;
#pragma unroll
        for (int jj = 0; jj < 4; ++jj) {
            int c4 = c4base + jj * 16;
            o4[c4] = make_float4(acc[jj].x * inv, acc[jj].y * inv,
                                 acc[jj].z * inv, acc[jj].w * inv);
        }
    } else {  // padded row inside a mixed tile
        const float inv = 1.0f / (float)S_;
        const float4* vs4 = (const float4*)&vsum[b * D_];
#pragma unroll
        for (int jj = 0; jj < 4; ++jj) {
            int c4 = c4base + jj * 16;
            float4 vv = vs4[c4];
            o4[c4] = make_float4(vv.x * inv, vv.y * inv, vv.z * inv, vv.w * inv);
        }
    }
}

// ---------------------------------------------------------------------------
extern "C" void kernel_launch(void* const* d_in, const int* in_sizes, int n_in,
                              void* d_out, int out_size, void* d_ws, size_t ws_size,
                              hipStream_t stream) {
    const float*   x    = (const float*)d_in[0];
    const uint8_t* mask = (const uint8_t*)d_in[1];
    const float*   Wq   = (const float*)d_in[2];
    const float*   bq   = (const float*)d_in[3];
    const float*   Wk   = (const float*)d_in[4];
    const float*   bk   = (const float*)d_in[5];
    const float*   Wv   = (const float*)d_in[6];
    const float*   bv   = (const float*)d_in[7];
    float* out = (float*)d_out;

    float* ws   = (float*)d_ws;
    float* q    = ws;                                   // 8192*128
    float* k    = ws + (size_t)8192 * 128;              // 8192*128
    float* v    = ws + (size_t)8192 * 128 * 2;          // 8192*1024
    float* vsum = v + (size_t)8192 * 1024;              // 4096
    int* lengths = (int*)(vsum + 4096);                 // 4

    hipMemsetAsync(vsum, 0, 4096 * sizeof(float), stream);
    lengths_kernel<<<dim3(B_), dim3(256), 0, stream>>>(mask, lengths);

    gemm_bias<<<dim3(DK_ / BN, (B_ * S_) / BM), 256, 0, stream>>>(x, Wq, bq, q, B_ * S_, DK_, D_);
    gemm_bias<<<dim3(DK_ / BN, (B_ * S_) / BM), 256, 0, stream>>>(x, Wk, bk, k, B_ * S_, DK_, D_);
    gemm_bias<<<dim3(D_ / BN, (B_ * S_) / BM), 256, 0, stream>>>(x, Wv, bv, v, B_ * S_, D_, D_);

    vsum_kernel<<<dim3(D_ / 256, B_, 8), 256, 0, stream>>>(v, vsum);

    flash_attn<<<dim3(S_ / 16, B_, NSLICE), 256, 0, stream>>>(q, k, v, vsum, lengths, out);
}

// Round 4
// 844.717 us; speedup vs baseline: 2.7627x; 1.9641x over previous
//
#include <hip/hip_runtime.h>
#include <cstdint>
#include <cstddef>

#define B_  4
#define S_  2048
#define D_  1024
#define DK_ 128

typedef float  f32x4   __attribute__((ext_vector_type(4)));
typedef short  bf16x8s __attribute__((ext_vector_type(8)));
typedef unsigned int   u32;
typedef unsigned short u16;

// ----- bf16 helpers (manual RNE; values bounded, no NaN/Inf) -----
__device__ inline u32 rne(float f) {
    u32 u = __builtin_bit_cast(u32, f);
    return (u + 0x7fffu + ((u >> 16) & 1u)) >> 16;
}
__device__ inline u32 pack2(float a, float b) { return rne(a) | (rne(b) << 16); }
__device__ inline bf16x8s ldfrag(const u16* p) {
    union { uint4 u; bf16x8s v; } c;
    c.u = *(const uint4*)p;
    return c.v;
}
__device__ inline f32x4 MM(bf16x8s a, bf16x8s b, f32x4 c) {
    return __builtin_amdgcn_mfma_f32_16x16x32_bf16(a, b, c, 0, 0, 0);
}

// ---------------------------------------------------------------------------
// lengths[b] (bool mask may be 1-byte or int32; byte S_-1 discriminates)
// ---------------------------------------------------------------------------
__global__ void lengths_kernel(const uint8_t* __restrict__ mask,
                               int* __restrict__ lengths) {
    int b = blockIdx.x;
    bool is_i32 = (mask[S_ - 1] == 0);
    __shared__ int cnt[256];
    int t = threadIdx.x;
    int c = 0;
    for (int i = t; i < S_; i += 256) {
        int val;
        if (is_i32) val = ((const int*)mask)[b * S_ + i];
        else        val = mask[b * S_ + i];
        c += (val == 0) ? 1 : 0;
    }
    cnt[t] = c;
    __syncthreads();
    for (int s = 128; s > 0; s >>= 1) {
        if (t < s) cnt[t] += cnt[t + s];
        __syncthreads();
    }
    if (t == 0) lengths[b] = cnt[0];
}

// ---------------------------------------------------------------------------
// fp32 -> bf16, 4 per thread
// ---------------------------------------------------------------------------
__global__ __launch_bounds__(256) void tobf16_kernel(
    const float* __restrict__ in, u16* __restrict__ out) {
    size_t i = (size_t)blockIdx.x * 256 + threadIdx.x;
    float4 f = ((const float4*)in)[i];
    ushort4 o = { (u16)rne(f.x), (u16)rne(f.y), (u16)rne(f.z), (u16)rne(f.w) };
    ((ushort4*)out)[i] = o;
}

// ---------------------------------------------------------------------------
// transpose + bf16: W[K][N] fp32 -> WT[N][K] bf16
// ---------------------------------------------------------------------------
__global__ __launch_bounds__(256) void transpose_tobf16_kernel(
    const float* __restrict__ W, u16* __restrict__ T, int K, int N) {
    __shared__ float tl[32][33];
    const int t = threadIdx.x, tx = t & 31, ty = t >> 5;
    const int n0 = blockIdx.x * 32, k0 = blockIdx.y * 32;
#pragma unroll
    for (int i = 0; i < 4; ++i)
        tl[ty + i * 8][tx] = W[(size_t)(k0 + ty + i * 8) * N + n0 + tx];
    __syncthreads();
#pragma unroll
    for (int i = 0; i < 4; ++i) {
        float f = tl[tx][ty + i * 8];
        T[(size_t)(n0 + ty + i * 8) * K + k0 + tx] = (u16)rne(f);
    }
}

// ---------------------------------------------------------------------------
// NT-GEMM bf16: C[m][n] = (sum_k A[m][k]*B[n][k] + bias)*scale, C bf16.
// 4 waves 2x2, wave tile WM x WN, 16x16x32 MFMA, no LDS (L1/L2 reuse).
// ---------------------------------------------------------------------------
template<int BM, int BN, int WM, int WN>
__global__ __launch_bounds__(256) void gemm_nt(
    const u16* __restrict__ A, const u16* __restrict__ Bm,
    const float* __restrict__ bias_col, const float* __restrict__ bias_row,
    float scale, u16* __restrict__ C, int N, int K,
    size_t bStride, size_t cStride)
{
    constexpr int FM = WM / 16, FN = WN / 16;
    const int t = threadIdx.x, w = t >> 6, lane = t & 63;
    const int g = lane >> 4, c16 = lane & 15;
    const int m0 = blockIdx.y * BM + (w >> 1) * WM;
    const int n0 = blockIdx.x * BN + (w & 1) * WN;
    Bm += blockIdx.z * bStride;
    C  += blockIdx.z * cStride;

    f32x4 acc[FM][FN];
#pragma unroll
    for (int i = 0; i < FM; ++i)
#pragma unroll
        for (int j = 0; j < FN; ++j) acc[i][j] = (f32x4){0.f, 0.f, 0.f, 0.f};

    size_t aoff[FM], boff[FN];
#pragma unroll
    for (int i = 0; i < FM; ++i) aoff[i] = (size_t)(m0 + i * 16 + c16) * K + g * 8;
#pragma unroll
    for (int j = 0; j < FN; ++j) boff[j] = (size_t)(n0 + j * 16 + c16) * K + g * 8;

#pragma unroll 2
    for (int k0 = 0; k0 < K; k0 += 32) {
        bf16x8s a[FM], b[FN];
#pragma unroll
        for (int i = 0; i < FM; ++i) a[i] = ldfrag(A + aoff[i] + k0);
#pragma unroll
        for (int j = 0; j < FN; ++j) b[j] = ldfrag(Bm + boff[j] + k0);
#pragma unroll
        for (int i = 0; i < FM; ++i)
#pragma unroll
            for (int j = 0; j < FN; ++j)
                acc[i][j] = MM(a[i], b[j], acc[i][j]);
    }

#pragma unroll
    for (int i = 0; i < FM; ++i)
#pragma unroll
        for (int j = 0; j < FN; ++j) {
            const int n = n0 + j * 16 + c16;
            const float bc = bias_col ? bias_col[n] : 0.f;
#pragma unroll
            for (int r = 0; r < 4; ++r) {
                const int m = m0 + i * 16 + g * 4 + r;
                const float br = bias_row ? bias_row[m] : 0.f;
                float val = (acc[i][j][r] + bc + br) * scale;
                C[(size_t)m * N + n] = (u16)rne(val);
            }
        }
}

// ---------------------------------------------------------------------------
// vsumf[b][d] = sum_s VT[b][d][s]   (one wave per row)
// ---------------------------------------------------------------------------
__global__ __launch_bounds__(64) void vsum_rows_kernel(
    const u16* __restrict__ vt, float* __restrict__ vsumf) {
    const int blk = blockIdx.x;            // b*1024 + d
    const int lane = threadIdx.x;
    const u16* rr = vt + (size_t)blk * S_;
    float s = 0.f;
    for (int ch = lane; ch < S_ / 8; ch += 64) {
        union { uint4 u; u16 e[8]; } a;
        a.u = ((const uint4*)rr)[ch];
#pragma unroll
        for (int j = 0; j < 8; ++j)
            s += __builtin_bit_cast(float, (u32)a.e[j] << 16);
    }
#pragma unroll
    for (int off = 1; off < 64; off <<= 1) s += __shfl_xor(s, off);
    if (lane == 0) vsumf[blk] = s;
}

// ---------------------------------------------------------------------------
// MFMA flash attention, bf16. Grid (32 q-tiles of 64, B, 4 d-slices of 256).
// 4 waves; wave w owns q rows r0+w*16..+15. Zero LDS; waves independent.
//
// Swapped QK^T with PERMUTED K-row loads: for score-tile kt, the A-operand
// (K) row c16 is key keyloc = (c16>>2)*8 + kt*4 + (c16&3). Then S^T's
// C-layout reg r at lane group g holds key kb + g*8 + kt*4 + r, i.e. the
// two tiles together give each lane exactly the A-fragment key octet
// g*8..g*8+7 for PV -- no cross-lane P routing at all.
//
// Online softmax per q row (lane c16): reduce across g via xor16/xor32.
// PV acc C-layout has q on the REG axis (row = g*4+r), so the rescale
// factor must be shuffled to reg rows (R3's bug: used the lane's own sc).
// Defer-rescale (T13, THR=8) skips the rescale when max growth is small.
// ---------------------------------------------------------------------------
__global__ __launch_bounds__(256) void flash_mfma(
    const u16* __restrict__ qb, const u16* __restrict__ kbuf,
    const u16* __restrict__ vt, const float* __restrict__ vsumf,
    const int* __restrict__ lengths, float* __restrict__ out)
{
    const int b     = blockIdx.y;
    const int slice = blockIdx.z;
    const int tile  = (int)gridDim.x - 1 - (int)blockIdx.x;  // big tiles first
    const int r0    = tile * 64;
    const int t = threadIdx.x, w = t >> 6, lane = t & 63;
    const int g = lane >> 4, c16 = lane & 15;
    const int len = lengths[b];

    if (r0 >= len) {  // whole 64-row tile padded: rows = mean(v)
        const float inv = 1.0f / (float)S_;
        const float4* vs4 = (const float4*)(vsumf + (size_t)b * D_ + slice * 256);
        float4 vv = vs4[lane];
        float4 o = { vv.x * inv, vv.y * inv, vv.z * inv, vv.w * inv };
        for (int r = w; r < 64; r += 4)
            ((float4*)(out + ((size_t)(b * S_ + r0 + r)) * D_ + slice * 256))[lane] = o;
        return;
    }

    const int qr = r0 + w * 16;       // wave's q-row base
    const int qg = qr + c16;          // this lane's softmax q row

    // Q B-fragments (hoisted)
    bf16x8s Q[4];
    {
        const size_t qrow = (size_t)(b * S_ + qr + c16) * DK_;
#pragma unroll
        for (int dt = 0; dt < 4; ++dt)
            Q[dt] = ldfrag(qb + qrow + dt * 32 + g * 8);
    }

    f32x4 acc[16];
#pragma unroll
    for (int i = 0; i < 16; ++i) acc[i] = (f32x4){0.f, 0.f, 0.f, 0.f};
    float m_r = -3.0e38f, l_r = 0.f;

    const int keyloc0 = ((c16 >> 2) << 3) + (c16 & 3);  // kt=0 permuted key row

    const int kmax_w = (qr >= len) ? -1 : min(qr + 15, len - 1);
    for (int kb = 0; kb <= kmax_w; kb += 32) {
        // ---- S^T = K . Q^T, permuted K rows ----
        f32x4 sT[2];
#pragma unroll
        for (int kt = 0; kt < 2; ++kt) {
            const size_t krow = (size_t)(b * S_ + kb + keyloc0 + kt * 4) * DK_;
            f32x4 s = (f32x4){0.f, 0.f, 0.f, 0.f};
#pragma unroll
            for (int dt = 0; dt < 4; ++dt)
                s = MM(ldfrag(kbuf + krow + dt * 32 + g * 8), Q[dt], s);
            sT[kt] = s;
        }
        // ---- causal mask: reg r of tile kt = key kb + g*8 + kt*4 + r ----
#pragma unroll
        for (int kt = 0; kt < 2; ++kt)
#pragma unroll
            for (int r = 0; r < 4; ++r) {
                int key = kb + g * 8 + kt * 4 + r;
                if (key > qg) sT[kt][r] = -3.0e38f;
            }
        // ---- online softmax over key axis (per q row = lane c16) ----
        float cmax = sT[0][0];
#pragma unroll
        for (int r = 1; r < 4; ++r) cmax = fmaxf(cmax, sT[0][r]);
#pragma unroll
        for (int r = 0; r < 4; ++r) cmax = fmaxf(cmax, sT[1][r]);
        cmax = fmaxf(cmax, __shfl_xor(cmax, 16));
        cmax = fmaxf(cmax, __shfl_xor(cmax, 32));

        const bool noresc = __all(cmax <= m_r + 8.0f);  // defer-rescale (T13)
        float m_new = m_r, sc = 1.0f;
        if (!noresc) {
            m_new = fmaxf(m_r, cmax);
            sc = __expf(m_r - m_new);
        }

        float p[2][4];
        float rs = 0.f;
#pragma unroll
        for (int kt = 0; kt < 2; ++kt)
#pragma unroll
            for (int r = 0; r < 4; ++r) {
                p[kt][r] = __expf(sT[kt][r] - m_new);
                rs += p[kt][r];
            }
        rs += __shfl_xor(rs, 16);
        rs += __shfl_xor(rs, 32);

        if (!noresc) {
            // acc q rows are REG-indexed (row = g*4+r): fetch each row's sc
            float scr0 = __shfl(sc, g * 4 + 0, 16);
            float scr1 = __shfl(sc, g * 4 + 1, 16);
            float scr2 = __shfl(sc, g * 4 + 2, 16);
            float scr3 = __shfl(sc, g * 4 + 3, 16);
            f32x4 scv = { scr0, scr1, scr2, scr3 };
#pragma unroll
            for (int i = 0; i < 16; ++i) acc[i] *= scv;
            l_r = l_r * sc + rs;
            m_r = m_new;
        } else {
            l_r += rs;
        }

        // ---- pack P into A-fragment octet (all lane-local) ----
        union { u32 wrd[4]; bf16x8s v; } pa;
        pa.wrd[0] = pack2(p[0][0], p[0][1]);
        pa.wrd[1] = pack2(p[0][2], p[0][3]);
        pa.wrd[2] = pack2(p[1][0], p[1][1]);
        pa.wrd[3] = pack2(p[1][2], p[1][3]);

        // ---- PV over this block's 256-col slice ----
#pragma unroll 4
        for (int cg = 0; cg < 16; ++cg) {
            const size_t vrow =
                (size_t)(b * D_ + slice * 256 + cg * 16 + c16) * S_ + kb + g * 8;
            acc[cg] = MM(pa.v, ldfrag(vt + vrow), acc[cg]);
        }
    }

    // ---- epilogue: C rows = q (reg axis), cols = d (lane axis) ----
    const float linv = 1.0f / l_r;
    float iv[4];
    bool valid[4];
#pragma unroll
    for (int r = 0; r < 4; ++r) {
        const int row = g * 4 + r;
        iv[r] = __shfl(linv, row, 16);
        valid[r] = (qr + row) < len;
    }
    const float invS = 1.0f / (float)S_;
#pragma unroll
    for (int cg = 0; cg < 16; ++cg) {
        const int d = slice * 256 + cg * 16 + c16;
        const float vsv = vsumf[(size_t)b * D_ + d] * invS;
#pragma unroll
        for (int r = 0; r < 4; ++r) {
            const int rowg = qr + g * 4 + r;
            const float val = valid[r] ? acc[cg][r] * iv[r] : vsv;
            out[((size_t)(b * S_ + rowg)) * D_ + d] = val;
        }
    }
}

// ---------------------------------------------------------------------------
extern "C" void kernel_launch(void* const* d_in, const int* in_sizes, int n_in,
                              void* d_out, int out_size, void* d_ws, size_t ws_size,
                              hipStream_t stream) {
    const float*   x    = (const float*)d_in[0];
    const uint8_t* mask = (const uint8_t*)d_in[1];
    const float*   Wq   = (const float*)d_in[2];
    const float*   bq   = (const float*)d_in[3];
    const float*   Wk   = (const float*)d_in[4];
    const float*   bk   = (const float*)d_in[5];
    const float*   Wv   = (const float*)d_in[6];
    const float*   bv   = (const float*)d_in[7];
    float* out = (float*)d_out;

    // workspace (u16 planes), total ~40.4 MB (<= R2's proven 42 MB)
    u16* u = (u16*)d_ws;
    u16* x_bf = u;                    u += (size_t)8192 * 1024;
    u16* wqt  = u;                    u += (size_t)128 * 1024;
    u16* wkt  = u;                    u += (size_t)128 * 1024;
    u16* wvt  = u;                    u += (size_t)1024 * 1024;
    u16* qb   = u;                    u += (size_t)8192 * 128;
    u16* kbuf = u;                    u += (size_t)8192 * 128;
    u16* vt   = u;                    u += (size_t)B_ * 1024 * 2048;
    float* vsumf = (float*)u;
    int* lengths = (int*)(vsumf + B_ * D_);

    const float SCALE = 0.08838834764831845f;  // 1/sqrt(128)

    lengths_kernel<<<dim3(B_), dim3(256), 0, stream>>>(mask, lengths);
    tobf16_kernel<<<dim3(8192), dim3(256), 0, stream>>>(x, x_bf);
    transpose_tobf16_kernel<<<dim3(4, 32), dim3(256), 0, stream>>>(Wq, wqt, 1024, 128);
    transpose_tobf16_kernel<<<dim3(4, 32), dim3(256), 0, stream>>>(Wk, wkt, 1024, 128);
    transpose_tobf16_kernel<<<dim3(32, 32), dim3(256), 0, stream>>>(Wv, wvt, 1024, 1024);

    // q = (x@Wq + bq)*scale ; k = x@Wk + bk    ([8192][128] bf16)
    gemm_nt<64, 64, 32, 32><<<dim3(2, 128, 1), dim3(256), 0, stream>>>(
        x_bf, wqt, bq, nullptr, SCALE, qb, 128, 1024, 0, 0);
    gemm_nt<64, 64, 32, 32><<<dim3(2, 128, 1), dim3(256), 0, stream>>>(
        x_bf, wkt, bk, nullptr, 1.0f, kbuf, 128, 1024, 0, 0);
    // VT[b] = Wv^T @ x[b]^T + bv[d]   ([1024 d][2048 tok] bf16, per batch)
    gemm_nt<128, 128, 64, 64><<<dim3(16, 8, B_), dim3(256), 0, stream>>>(
        wvt, x_bf, nullptr, bv, 1.0f, vt, 2048, 1024,
        (size_t)2048 * 1024, (size_t)1024 * 2048);

    vsum_rows_kernel<<<dim3(B_ * D_), dim3(64), 0, stream>>>(vt, vsumf);

    flash_mfma<<<dim3(S_ / 64, B_, 4), dim3(256), 0, stream>>>(
        qb, kbuf, vt, vsumf, lengths, out);
}

// Round 5
// 508.180 us; speedup vs baseline: 4.5922x; 1.6622x over previous
//
#include <hip/hip_runtime.h>
#include <cstdint>
#include <cstddef>

#define B_  4
#define S_  2048
#define D_  1024
#define DK_ 128

typedef float  f32x4   __attribute__((ext_vector_type(4)));
typedef short  bf16x8s __attribute__((ext_vector_type(8)));
typedef unsigned int   u32;
typedef unsigned short u16;

// ----- bf16 helpers (manual RNE; values bounded, no NaN/Inf) -----
__device__ inline u32 rne(float f) {
    u32 u = __builtin_bit_cast(u32, f);
    return (u + 0x7fffu + ((u >> 16) & 1u)) >> 16;
}
__device__ inline u32 pack2(float a, float b) { return rne(a) | (rne(b) << 16); }
__device__ inline bf16x8s ldfrag(const u16* p) {
    union { uint4 u; bf16x8s v; } c;
    c.u = *(const uint4*)p;
    return c.v;
}
__device__ inline f32x4 MM(bf16x8s a, bf16x8s b, f32x4 c) {
    return __builtin_amdgcn_mfma_f32_16x16x32_bf16(a, b, c, 0, 0, 0);
}

// ---------------------------------------------------------------------------
// lengths[b] (bool mask may be 1-byte or int32; byte S_-1 discriminates)
// ---------------------------------------------------------------------------
__global__ void lengths_kernel(const uint8_t* __restrict__ mask,
                               int* __restrict__ lengths) {
    int b = blockIdx.x;
    bool is_i32 = (mask[S_ - 1] == 0);
    __shared__ int cnt[256];
    int t = threadIdx.x;
    int c = 0;
    for (int i = t; i < S_; i += 256) {
        int val;
        if (is_i32) val = ((const int*)mask)[b * S_ + i];
        else        val = mask[b * S_ + i];
        c += (val == 0) ? 1 : 0;
    }
    cnt[t] = c;
    __syncthreads();
    for (int s = 128; s > 0; s >>= 1) {
        if (t < s) cnt[t] += cnt[t + s];
        __syncthreads();
    }
    if (t == 0) lengths[b] = cnt[0];
}

// ---------------------------------------------------------------------------
// fp32 -> bf16, 4 per thread
// ---------------------------------------------------------------------------
__global__ __launch_bounds__(256) void tobf16_kernel(
    const float* __restrict__ in, u16* __restrict__ out) {
    size_t i = (size_t)blockIdx.x * 256 + threadIdx.x;
    float4 f = ((const float4*)in)[i];
    ushort4 o = { (u16)rne(f.x), (u16)rne(f.y), (u16)rne(f.z), (u16)rne(f.w) };
    ((ushort4*)out)[i] = o;
}

// ---------------------------------------------------------------------------
// transpose + bf16: W[K][N] fp32 -> WT[N][K] bf16
// ---------------------------------------------------------------------------
__global__ __launch_bounds__(256) void transpose_tobf16_kernel(
    const float* __restrict__ W, u16* __restrict__ T, int K, int N) {
    __shared__ float tl[32][33];
    const int t = threadIdx.x, tx = t & 31, ty = t >> 5;
    const int n0 = blockIdx.x * 32, k0 = blockIdx.y * 32;
#pragma unroll
    for (int i = 0; i < 4; ++i)
        tl[ty + i * 8][tx] = W[(size_t)(k0 + ty + i * 8) * N + n0 + tx];
    __syncthreads();
#pragma unroll
    for (int i = 0; i < 4; ++i) {
        float f = tl[tx][ty + i * 8];
        T[(size_t)(n0 + ty + i * 8) * K + k0 + tx] = (u16)rne(f);
    }
}

// ---------------------------------------------------------------------------
// NT-GEMM bf16: C[m][n] = (sum_k A[m][k]*B[n][k] + bias)*scale, C bf16.
// 4 waves 2x2, wave tile WM x WN, 16x16x32 MFMA, no LDS (L1/L2 reuse).
// ---------------------------------------------------------------------------
template<int BM, int BN, int WM, int WN>
__global__ __launch_bounds__(256) void gemm_nt(
    const u16* __restrict__ A, const u16* __restrict__ Bm,
    const float* __restrict__ bias_col, const float* __restrict__ bias_row,
    float scale, u16* __restrict__ C, int N, int K,
    size_t bStride, size_t cStride)
{
    constexpr int FM = WM / 16, FN = WN / 16;
    const int t = threadIdx.x, w = t >> 6, lane = t & 63;
    const int g = lane >> 4, c16 = lane & 15;
    const int m0 = blockIdx.y * BM + (w >> 1) * WM;
    const int n0 = blockIdx.x * BN + (w & 1) * WN;
    Bm += blockIdx.z * bStride;
    C  += blockIdx.z * cStride;

    f32x4 acc[FM][FN];
#pragma unroll
    for (int i = 0; i < FM; ++i)
#pragma unroll
        for (int j = 0; j < FN; ++j) acc[i][j] = (f32x4){0.f, 0.f, 0.f, 0.f};

    size_t aoff[FM], boff[FN];
#pragma unroll
    for (int i = 0; i < FM; ++i) aoff[i] = (size_t)(m0 + i * 16 + c16) * K + g * 8;
#pragma unroll
    for (int j = 0; j < FN; ++j) boff[j] = (size_t)(n0 + j * 16 + c16) * K + g * 8;

#pragma unroll 2
    for (int k0 = 0; k0 < K; k0 += 32) {
        bf16x8s a[FM], b[FN];
#pragma unroll
        for (int i = 0; i < FM; ++i) a[i] = ldfrag(A + aoff[i] + k0);
#pragma unroll
        for (int j = 0; j < FN; ++j) b[j] = ldfrag(Bm + boff[j] + k0);
#pragma unroll
        for (int i = 0; i < FM; ++i)
#pragma unroll
            for (int j = 0; j < FN; ++j)
                acc[i][j] = MM(a[i], b[j], acc[i][j]);
    }

#pragma unroll
    for (int i = 0; i < FM; ++i)
#pragma unroll
        for (int j = 0; j < FN; ++j) {
            const int n = n0 + j * 16 + c16;
            const float bc = bias_col ? bias_col[n] : 0.f;
#pragma unroll
            for (int r = 0; r < 4; ++r) {
                const int m = m0 + i * 16 + g * 4 + r;
                const float br = bias_row ? bias_row[m] : 0.f;
                float val = (acc[i][j][r] + bc + br) * scale;
                C[(size_t)m * N + n] = (u16)rne(val);
            }
        }
}

// ---------------------------------------------------------------------------
// vsumf[b][d] = sum_s VT[b][d][s]   (one wave per row)
// ---------------------------------------------------------------------------
__global__ __launch_bounds__(64) void vsum_rows_kernel(
    const u16* __restrict__ vt, float* __restrict__ vsumf) {
    const int blk = blockIdx.x;            // b*1024 + d
    const int lane = threadIdx.x;
    const u16* rr = vt + (size_t)blk * S_;
    float s = 0.f;
    for (int ch = lane; ch < S_ / 8; ch += 64) {
        union { uint4 u; u16 e[8]; } a;
        a.u = ((const uint4*)rr)[ch];
#pragma unroll
        for (int j = 0; j < 8; ++j)
            s += __builtin_bit_cast(float, (u32)a.e[j] << 16);
    }
#pragma unroll
    for (int off = 1; off < 64; off <<= 1) s += __shfl_xor(s, off);
    if (lane == 0) vsumf[blk] = s;
}

// ---------------------------------------------------------------------------
// MFMA flash attention, bf16. Grid (32 q-tiles of 64, B, 4 d-slices of 256).
// 4 waves; wave w owns q rows r0+w*16..+15. Zero LDS; waves independent.
//
// Swapped QK^T with PERMUTED K-row loads: for score-tile kt, the A-operand
// (K) row c16 is key keyloc = (c16>>2)*8 + kt*4 + (c16&3). Then S^T's
// C-layout reg r at lane group g holds key kb + g*8 + kt*4 + r, i.e. the
// two tiles together give each lane exactly the A-fragment key octet
// g*8..g*8+7 for PV -- no cross-lane P routing at all.
//
// Online softmax per q row (lane c16): reduce across g via xor16/xor32.
// PV acc C-layout has q on the REG axis (row = g*4+r): rescale factor is
// shuffled to reg rows. Defer-rescale (T13, THR=8) skips it when possible.
//
// R5 fix: PV loop FULLY unrolled -- a partial unroll (R4) left `cg` a
// runtime index into acc[16], forcing acc to scratch (rule #20): VGPR=32,
// WRITE_SIZE 715 MB of spill traffic, 645 us. All acc indices must be
// compile-time.
// ---------------------------------------------------------------------------
__global__ __launch_bounds__(256) void flash_mfma(
    const u16* __restrict__ qb, const u16* __restrict__ kbuf,
    const u16* __restrict__ vt, const float* __restrict__ vsumf,
    const int* __restrict__ lengths, float* __restrict__ out)
{
    const int b     = blockIdx.y;
    const int slice = blockIdx.z;
    const int tile  = (int)gridDim.x - 1 - (int)blockIdx.x;  // big tiles first
    const int r0    = tile * 64;
    const int t = threadIdx.x, w = t >> 6, lane = t & 63;
    const int g = lane >> 4, c16 = lane & 15;
    const int len = lengths[b];

    if (r0 >= len) {  // whole 64-row tile padded: rows = mean(v)
        const float inv = 1.0f / (float)S_;
        const float4* vs4 = (const float4*)(vsumf + (size_t)b * D_ + slice * 256);
        float4 vv = vs4[lane];
        float4 o = { vv.x * inv, vv.y * inv, vv.z * inv, vv.w * inv };
        for (int r = w; r < 64; r += 4)
            ((float4*)(out + ((size_t)(b * S_ + r0 + r)) * D_ + slice * 256))[lane] = o;
        return;
    }

    const int qr = r0 + w * 16;       // wave's q-row base
    const int qg = qr + c16;          // this lane's softmax q row

    // Q B-fragments (hoisted)
    bf16x8s Q[4];
    {
        const size_t qrow = (size_t)(b * S_ + qr + c16) * DK_;
#pragma unroll
        for (int dt = 0; dt < 4; ++dt)
            Q[dt] = ldfrag(qb + qrow + dt * 32 + g * 8);
    }

    f32x4 acc[16];
#pragma unroll
    for (int i = 0; i < 16; ++i) acc[i] = (f32x4){0.f, 0.f, 0.f, 0.f};
    float m_r = -3.0e38f, l_r = 0.f;

    const int keyloc0 = ((c16 >> 2) << 3) + (c16 & 3);  // kt=0 permuted key row

    const int kmax_w = (qr >= len) ? -1 : min(qr + 15, len - 1);
    for (int kb = 0; kb <= kmax_w; kb += 32) {
        // ---- S^T = K . Q^T, permuted K rows ----
        f32x4 sT[2];
#pragma unroll
        for (int kt = 0; kt < 2; ++kt) {
            const size_t krow = (size_t)(b * S_ + kb + keyloc0 + kt * 4) * DK_;
            f32x4 s = (f32x4){0.f, 0.f, 0.f, 0.f};
#pragma unroll
            for (int dt = 0; dt < 4; ++dt)
                s = MM(ldfrag(kbuf + krow + dt * 32 + g * 8), Q[dt], s);
            sT[kt] = s;
        }
        // ---- causal mask: reg r of tile kt = key kb + g*8 + kt*4 + r ----
#pragma unroll
        for (int kt = 0; kt < 2; ++kt)
#pragma unroll
            for (int r = 0; r < 4; ++r) {
                int key = kb + g * 8 + kt * 4 + r;
                if (key > qg) sT[kt][r] = -3.0e38f;
            }
        // ---- online softmax over key axis (per q row = lane c16) ----
        float cmax = sT[0][0];
#pragma unroll
        for (int r = 1; r < 4; ++r) cmax = fmaxf(cmax, sT[0][r]);
#pragma unroll
        for (int r = 0; r < 4; ++r) cmax = fmaxf(cmax, sT[1][r]);
        cmax = fmaxf(cmax, __shfl_xor(cmax, 16));
        cmax = fmaxf(cmax, __shfl_xor(cmax, 32));

        const bool noresc = __all(cmax <= m_r + 8.0f);  // defer-rescale (T13)
        float m_new = m_r, sc = 1.0f;
        if (!noresc) {
            m_new = fmaxf(m_r, cmax);
            sc = __expf(m_r - m_new);
        }

        float p[2][4];
        float rs = 0.f;
#pragma unroll
        for (int kt = 0; kt < 2; ++kt)
#pragma unroll
            for (int r = 0; r < 4; ++r) {
                p[kt][r] = __expf(sT[kt][r] - m_new);
                rs += p[kt][r];
            }
        rs += __shfl_xor(rs, 16);
        rs += __shfl_xor(rs, 32);

        if (!noresc) {
            // acc q rows are REG-indexed (row = g*4+r): fetch each row's sc
            float scr0 = __shfl(sc, g * 4 + 0, 16);
            float scr1 = __shfl(sc, g * 4 + 1, 16);
            float scr2 = __shfl(sc, g * 4 + 2, 16);
            float scr3 = __shfl(sc, g * 4 + 3, 16);
            f32x4 scv = { scr0, scr1, scr2, scr3 };
#pragma unroll
            for (int i = 0; i < 16; ++i) acc[i] *= scv;
            l_r = l_r * sc + rs;
            m_r = m_new;
        } else {
            l_r += rs;
        }

        // ---- pack P into A-fragment octet (all lane-local) ----
        union { u32 wrd[4]; bf16x8s v; } pa;
        pa.wrd[0] = pack2(p[0][0], p[0][1]);
        pa.wrd[1] = pack2(p[0][2], p[0][3]);
        pa.wrd[2] = pack2(p[1][0], p[1][1]);
        pa.wrd[3] = pack2(p[1][2], p[1][3]);

        // ---- PV over this block's 256-col slice (FULL unroll; rule #20) ----
        const size_t vbase = (size_t)(b * D_ + slice * 256 + c16) * S_ + kb + g * 8;
#pragma unroll
        for (int cg = 0; cg < 16; ++cg) {
            acc[cg] = MM(pa.v, ldfrag(vt + vbase + (size_t)cg * 16 * S_), acc[cg]);
        }
    }

    // ---- epilogue: C rows = q (reg axis), cols = d (lane axis) ----
    const float linv = 1.0f / l_r;
    float iv[4];
    bool valid[4];
#pragma unroll
    for (int r = 0; r < 4; ++r) {
        const int row = g * 4 + r;
        iv[r] = __shfl(linv, row, 16);
        valid[r] = (qr + row) < len;
    }
    const float invS = 1.0f / (float)S_;
#pragma unroll
    for (int cg = 0; cg < 16; ++cg) {
        const int d = slice * 256 + cg * 16 + c16;
        const float vsv = vsumf[(size_t)b * D_ + d] * invS;
#pragma unroll
        for (int r = 0; r < 4; ++r) {
            const int rowg = qr + g * 4 + r;
            const float val = valid[r] ? acc[cg][r] * iv[r] : vsv;
            out[((size_t)(b * S_ + rowg)) * D_ + d] = val;
        }
    }
}

// ---------------------------------------------------------------------------
extern "C" void kernel_launch(void* const* d_in, const int* in_sizes, int n_in,
                              void* d_out, int out_size, void* d_ws, size_t ws_size,
                              hipStream_t stream) {
    const float*   x    = (const float*)d_in[0];
    const uint8_t* mask = (const uint8_t*)d_in[1];
    const float*   Wq   = (const float*)d_in[2];
    const float*   bq   = (const float*)d_in[3];
    const float*   Wk   = (const float*)d_in[4];
    const float*   bk   = (const float*)d_in[5];
    const float*   Wv   = (const float*)d_in[6];
    const float*   bv   = (const float*)d_in[7];
    float* out = (float*)d_out;

    // workspace (u16 planes), total ~40.4 MB
    u16* u = (u16*)d_ws;
    u16* x_bf = u;                    u += (size_t)8192 * 1024;
    u16* wqt  = u;                    u += (size_t)128 * 1024;
    u16* wkt  = u;                    u += (size_t)128 * 1024;
    u16* wvt  = u;                    u += (size_t)1024 * 1024;
    u16* qb   = u;                    u += (size_t)8192 * 128;
    u16* kbuf = u;                    u += (size_t)8192 * 128;
    u16* vt   = u;                    u += (size_t)B_ * 1024 * 2048;
    float* vsumf = (float*)u;
    int* lengths = (int*)(vsumf + B_ * D_);

    const float SCALE = 0.08838834764831845f;  // 1/sqrt(128)

    lengths_kernel<<<dim3(B_), dim3(256), 0, stream>>>(mask, lengths);
    tobf16_kernel<<<dim3(8192), dim3(256), 0, stream>>>(x, x_bf);
    transpose_tobf16_kernel<<<dim3(4, 32), dim3(256), 0, stream>>>(Wq, wqt, 1024, 128);
    transpose_tobf16_kernel<<<dim3(4, 32), dim3(256), 0, stream>>>(Wk, wkt, 1024, 128);
    transpose_tobf16_kernel<<<dim3(32, 32), dim3(256), 0, stream>>>(Wv, wvt, 1024, 1024);

    // q = (x@Wq + bq)*scale ; k = x@Wk + bk    ([8192][128] bf16)
    gemm_nt<64, 64, 32, 32><<<dim3(2, 128, 1), dim3(256), 0, stream>>>(
        x_bf, wqt, bq, nullptr, SCALE, qb, 128, 1024, 0, 0);
    gemm_nt<64, 64, 32, 32><<<dim3(2, 128, 1), dim3(256), 0, stream>>>(
        x_bf, wkt, bk, nullptr, 1.0f, kbuf, 128, 1024, 0, 0);
    // VT[b] = Wv^T @ x[b]^T + bv[d]   ([1024 d][2048 tok] bf16, per batch)
    gemm_nt<128, 128, 64, 64><<<dim3(16, 8, B_), dim3(256), 0, stream>>>(
        wvt, x_bf, nullptr, bv, 1.0f, vt, 2048, 1024,
        (size_t)2048 * 1024, (size_t)1024 * 2048);

    vsum_rows_kernel<<<dim3(B_ * D_), dim3(64), 0, stream>>>(vt, vsumf);

    flash_mfma<<<dim3(S_ / 64, B_, 4), dim3(256), 0, stream>>>(
        qb, kbuf, vt, vsumf, lengths, out);
}

// Round 6
// 504.891 us; speedup vs baseline: 4.6221x; 1.0065x over previous
//
#include <hip/hip_runtime.h>
#include <cstdint>
#include <cstddef>

#define B_  4
#define S_  2048
#define D_  1024
#define DK_ 128

typedef float  f32x4   __attribute__((ext_vector_type(4)));
typedef short  bf16x8s __attribute__((ext_vector_type(8)));
typedef unsigned int   u32;
typedef unsigned short u16;

// ----- bf16 helpers (manual RNE; values bounded, no NaN/Inf) -----
__device__ inline u32 rne(float f) {
    u32 u = __builtin_bit_cast(u32, f);
    return (u + 0x7fffu + ((u >> 16) & 1u)) >> 16;
}
__device__ inline u32 pack2(float a, float b) { return rne(a) | (rne(b) << 16); }
__device__ inline bf16x8s ldfrag(const u16* p) {
    union { uint4 u; bf16x8s v; } c;
    c.u = *(const uint4*)p;
    return c.v;
}
__device__ inline f32x4 MM(bf16x8s a, bf16x8s b, f32x4 c) {
    return __builtin_amdgcn_mfma_f32_16x16x32_bf16(a, b, c, 0, 0, 0);
}

// ---------------------------------------------------------------------------
// lengths[b] (bool mask may be 1-byte or int32; byte S_-1 discriminates)
// ---------------------------------------------------------------------------
__global__ void lengths_kernel(const uint8_t* __restrict__ mask,
                               int* __restrict__ lengths) {
    int b = blockIdx.x;
    bool is_i32 = (mask[S_ - 1] == 0);
    __shared__ int cnt[256];
    int t = threadIdx.x;
    int c = 0;
    for (int i = t; i < S_; i += 256) {
        int val;
        if (is_i32) val = ((const int*)mask)[b * S_ + i];
        else        val = mask[b * S_ + i];
        c += (val == 0) ? 1 : 0;
    }
    cnt[t] = c;
    __syncthreads();
    for (int s = 128; s > 0; s >>= 1) {
        if (t < s) cnt[t] += cnt[t + s];
        __syncthreads();
    }
    if (t == 0) lengths[b] = cnt[0];
}

// ---------------------------------------------------------------------------
// fp32 -> bf16, 4 per thread
// ---------------------------------------------------------------------------
__global__ __launch_bounds__(256) void tobf16_kernel(
    const float* __restrict__ in, u16* __restrict__ out) {
    size_t i = (size_t)blockIdx.x * 256 + threadIdx.x;
    float4 f = ((const float4*)in)[i];
    ushort4 o = { (u16)rne(f.x), (u16)rne(f.y), (u16)rne(f.z), (u16)rne(f.w) };
    ((ushort4*)out)[i] = o;
}

// ---------------------------------------------------------------------------
// transpose + bf16: W[K][N] fp32 -> WT[N][K] bf16
// ---------------------------------------------------------------------------
__global__ __launch_bounds__(256) void transpose_tobf16_kernel(
    const float* __restrict__ W, u16* __restrict__ T, int K, int N) {
    __shared__ float tl[32][33];
    const int t = threadIdx.x, tx = t & 31, ty = t >> 5;
    const int n0 = blockIdx.x * 32, k0 = blockIdx.y * 32;
#pragma unroll
    for (int i = 0; i < 4; ++i)
        tl[ty + i * 8][tx] = W[(size_t)(k0 + ty + i * 8) * N + n0 + tx];
    __syncthreads();
#pragma unroll
    for (int i = 0; i < 4; ++i) {
        float f = tl[tx][ty + i * 8];
        T[(size_t)(n0 + ty + i * 8) * K + k0 + tx] = (u16)rne(f);
    }
}

// ---------------------------------------------------------------------------
// NT-GEMM bf16: C[m][n] = (sum_k A[m][k]*B[n][k] + bias)*scale, C bf16.
// 4 waves 2x2, wave tile WM x WN, 16x16x32 MFMA, no LDS (L1/L2 reuse).
// ---------------------------------------------------------------------------
template<int BM, int BN, int WM, int WN>
__global__ __launch_bounds__(256) void gemm_nt(
    const u16* __restrict__ A, const u16* __restrict__ Bm,
    const float* __restrict__ bias_col, const float* __restrict__ bias_row,
    float scale, u16* __restrict__ C, int N, int K,
    size_t bStride, size_t cStride)
{
    constexpr int FM = WM / 16, FN = WN / 16;
    const int t = threadIdx.x, w = t >> 6, lane = t & 63;
    const int g = lane >> 4, c16 = lane & 15;
    const int m0 = blockIdx.y * BM + (w >> 1) * WM;
    const int n0 = blockIdx.x * BN + (w & 1) * WN;
    Bm += blockIdx.z * bStride;
    C  += blockIdx.z * cStride;

    f32x4 acc[FM][FN];
#pragma unroll
    for (int i = 0; i < FM; ++i)
#pragma unroll
        for (int j = 0; j < FN; ++j) acc[i][j] = (f32x4){0.f, 0.f, 0.f, 0.f};

    size_t aoff[FM], boff[FN];
#pragma unroll
    for (int i = 0; i < FM; ++i) aoff[i] = (size_t)(m0 + i * 16 + c16) * K + g * 8;
#pragma unroll
    for (int j = 0; j < FN; ++j) boff[j] = (size_t)(n0 + j * 16 + c16) * K + g * 8;

#pragma unroll 2
    for (int k0 = 0; k0 < K; k0 += 32) {
        bf16x8s a[FM], b[FN];
#pragma unroll
        for (int i = 0; i < FM; ++i) a[i] = ldfrag(A + aoff[i] + k0);
#pragma unroll
        for (int j = 0; j < FN; ++j) b[j] = ldfrag(Bm + boff[j] + k0);
#pragma unroll
        for (int i = 0; i < FM; ++i)
#pragma unroll
            for (int j = 0; j < FN; ++j)
                acc[i][j] = MM(a[i], b[j], acc[i][j]);
    }

#pragma unroll
    for (int i = 0; i < FM; ++i)
#pragma unroll
        for (int j = 0; j < FN; ++j) {
            const int n = n0 + j * 16 + c16;
            const float bc = bias_col ? bias_col[n] : 0.f;
#pragma unroll
            for (int r = 0; r < 4; ++r) {
                const int m = m0 + i * 16 + g * 4 + r;
                const float br = bias_row ? bias_row[m] : 0.f;
                float val = (acc[i][j][r] + bc + br) * scale;
                C[(size_t)m * N + n] = (u16)rne(val);
            }
        }
}

// ---------------------------------------------------------------------------
// vsumf[b][d] = sum_s VT[b][d][s]   (one wave per row)
// ---------------------------------------------------------------------------
__global__ __launch_bounds__(64) void vsum_rows_kernel(
    const u16* __restrict__ vt, float* __restrict__ vsumf) {
    const int blk = blockIdx.x;            // b*1024 + d
    const int lane = threadIdx.x;
    const u16* rr = vt + (size_t)blk * S_;
    float s = 0.f;
    for (int ch = lane; ch < S_ / 8; ch += 64) {
        union { uint4 u; u16 e[8]; } a;
        a.u = ((const uint4*)rr)[ch];
#pragma unroll
        for (int j = 0; j < 8; ++j)
            s += __builtin_bit_cast(float, (u32)a.e[j] << 16);
    }
#pragma unroll
    for (int off = 1; off < 64; off <<= 1) s += __shfl_xor(s, off);
    if (lane == 0) vsumf[blk] = s;
}

// ---------------------------------------------------------------------------
// MFMA flash attention, bf16. Grid (32 q-tiles of 64, B, 4 d-slices of 256).
// 4 waves; wave w owns q rows r0+w*16..+15. Zero LDS; waves independent.
//
// Swapped QK^T with PERMUTED K-row loads (see R4 comments): S^T reg r of
// tile kt = key kb + g*8 + kt*4 + r -> P is directly the PV A-fragment
// octet, zero cross-lane routing.
//
// R6: software-pipelined k-loop (T14). Per iteration, issue order is
//   (1) 16 V loads for THIS iter  (oldest in vmcnt queue)
//   (2) 8 K loads for NEXT iter   (newest)
// then QK on in-register K (waits nothing), softmax (V latency hides
// under it), PV (compiler emits vmcnt(8): V done, next-K still in
// flight across the iteration boundary). K is double-buffered in two
// NAMED buffers KA/KB with the loop unrolled by 2 (rule #20: no runtime
// indexing into register arrays).
// ---------------------------------------------------------------------------
__global__ __launch_bounds__(256, 2) void flash_mfma(
    const u16* __restrict__ qb, const u16* __restrict__ kbuf,
    const u16* __restrict__ vt, const float* __restrict__ vsumf,
    const int* __restrict__ lengths, float* __restrict__ out)
{
    const int b     = blockIdx.y;
    const int slice = blockIdx.z;
    const int tile  = (int)gridDim.x - 1 - (int)blockIdx.x;  // big tiles first
    const int r0    = tile * 64;
    const int t = threadIdx.x, w = t >> 6, lane = t & 63;
    const int g = lane >> 4, c16 = lane & 15;
    const int len = lengths[b];

    if (r0 >= len) {  // whole 64-row tile padded: rows = mean(v)
        const float inv = 1.0f / (float)S_;
        const float4* vs4 = (const float4*)(vsumf + (size_t)b * D_ + slice * 256);
        float4 vv = vs4[lane];
        float4 o = { vv.x * inv, vv.y * inv, vv.z * inv, vv.w * inv };
        for (int r = w; r < 64; r += 4)
            ((float4*)(out + ((size_t)(b * S_ + r0 + r)) * D_ + slice * 256))[lane] = o;
        return;
    }

    const int qr = r0 + w * 16;       // wave's q-row base
    const int qg = qr + c16;          // this lane's softmax q row

    // Q B-fragments (hoisted)
    bf16x8s Q[4];
    {
        const size_t qrow = (size_t)(b * S_ + qr + c16) * DK_;
#pragma unroll
        for (int dt = 0; dt < 4; ++dt)
            Q[dt] = ldfrag(qb + qrow + dt * 32 + g * 8);
    }

    f32x4 acc[16];
#pragma unroll
    for (int i = 0; i < 16; ++i) acc[i] = (f32x4){0.f, 0.f, 0.f, 0.f};
    float m_r = -3.0e38f, l_r = 0.f;

    const int keyloc0 = ((c16 >> 2) << 3) + (c16 & 3);  // kt=0 permuted key row
    const int kmax_w = (qr >= len) ? -1 : min(qr + 15, len - 1);

// load K fragments for chunk `kkb` into buffer KBUF (8 frags: [kt*4+dt])
#define LOADK(KBUF, kkb) do {                                                  \
    const size_t krow_ = (size_t)(b * S_ + (kkb) + keyloc0) * DK_;             \
    _Pragma("unroll")                                                          \
    for (int dt = 0; dt < 4; ++dt) {                                           \
        KBUF[dt]     = ldfrag(kbuf + krow_ + dt * 32 + g * 8);                 \
        KBUF[4 + dt] = ldfrag(kbuf + krow_ + 4 * DK_ + dt * 32 + g * 8);       \
    }                                                                          \
} while (0)

// one k-chunk step: consume KC (current K frags), prefetch into KN
#define STEP(KC, KN, kkb) do {                                                 \
    /* (1) V loads for THIS chunk -- issued FIRST (oldest in queue) */         \
    bf16x8s Vf[16];                                                            \
    {                                                                          \
        const size_t vbase_ =                                                  \
            (size_t)(b * D_ + slice * 256 + c16) * S_ + (kkb) + g * 8;         \
        _Pragma("unroll")                                                      \
        for (int cg = 0; cg < 16; ++cg)                                        \
            Vf[cg] = ldfrag(vt + vbase_ + (size_t)cg * 16 * S_);               \
    }                                                                          \
    /* (2) K loads for NEXT chunk (newest; stay in flight through PV) */       \
    if ((kkb) + 32 <= kmax_w) LOADK(KN, (kkb) + 32);                           \
    /* (3) QK from in-register KC */                                           \
    f32x4 sT[2];                                                               \
    _Pragma("unroll")                                                          \
    for (int kt = 0; kt < 2; ++kt) {                                           \
        f32x4 s_ = (f32x4){0.f, 0.f, 0.f, 0.f};                                \
        _Pragma("unroll")                                                      \
        for (int dt = 0; dt < 4; ++dt)                                         \
            s_ = MM(KC[kt * 4 + dt], Q[dt], s_);                               \
        sT[kt] = s_;                                                           \
    }                                                                          \
    /* causal mask: reg r of tile kt = key kkb + g*8 + kt*4 + r */             \
    _Pragma("unroll")                                                          \
    for (int kt = 0; kt < 2; ++kt)                                             \
        _Pragma("unroll")                                                      \
        for (int r = 0; r < 4; ++r) {                                          \
            int key_ = (kkb) + g * 8 + kt * 4 + r;                             \
            if (key_ > qg) sT[kt][r] = -3.0e38f;                               \
        }                                                                      \
    /* (4) online softmax over key axis (per q row = lane c16) */              \
    float cmax = sT[0][0];                                                     \
    _Pragma("unroll")                                                          \
    for (int r = 1; r < 4; ++r) cmax = fmaxf(cmax, sT[0][r]);                  \
    _Pragma("unroll")                                                          \
    for (int r = 0; r < 4; ++r) cmax = fmaxf(cmax, sT[1][r]);                  \
    cmax = fmaxf(cmax, __shfl_xor(cmax, 16));                                  \
    cmax = fmaxf(cmax, __shfl_xor(cmax, 32));                                  \
    const bool noresc = __all(cmax <= m_r + 8.0f);  /* defer-rescale T13 */    \
    float m_new = m_r, sc = 1.0f;                                              \
    if (!noresc) {                                                             \
        m_new = fmaxf(m_r, cmax);                                              \
        sc = __expf(m_r - m_new);                                              \
    }                                                                          \
    float p_[2][4];                                                            \
    float rs = 0.f;                                                            \
    _Pragma("unroll")                                                          \
    for (int kt = 0; kt < 2; ++kt)                                             \
        _Pragma("unroll")                                                      \
        for (int r = 0; r < 4; ++r) {                                          \
            p_[kt][r] = __expf(sT[kt][r] - m_new);                             \
            rs += p_[kt][r];                                                   \
        }                                                                      \
    rs += __shfl_xor(rs, 16);                                                  \
    rs += __shfl_xor(rs, 32);                                                  \
    if (!noresc) {                                                             \
        /* acc q rows are REG-indexed (row = g*4+r): per-row sc */             \
        float scr0 = __shfl(sc, g * 4 + 0, 16);                                \
        float scr1 = __shfl(sc, g * 4 + 1, 16);                                \
        float scr2 = __shfl(sc, g * 4 + 2, 16);                                \
        float scr3 = __shfl(sc, g * 4 + 3, 16);                                \
        f32x4 scv = { scr0, scr1, scr2, scr3 };                                \
        _Pragma("unroll")                                                      \
        for (int i = 0; i < 16; ++i) acc[i] *= scv;                            \
        l_r = l_r * sc + rs;                                                   \
        m_r = m_new;                                                           \
    } else {                                                                   \
        l_r += rs;                                                             \
    }                                                                          \
    /* (5) pack P into A-fragment octet (lane-local) */                        \
    union { u32 wrd[4]; bf16x8s v; } pa;                                       \
    pa.wrd[0] = pack2(p_[0][0], p_[0][1]);                                     \
    pa.wrd[1] = pack2(p_[0][2], p_[0][3]);                                     \
    pa.wrd[2] = pack2(p_[1][0], p_[1][1]);                                     \
    pa.wrd[3] = pack2(p_[1][2], p_[1][3]);                                     \
    /* (6) PV: vmcnt leaves next-K in flight */                                \
    _Pragma("unroll")                                                          \
    for (int cg = 0; cg < 16; ++cg)                                            \
        acc[cg] = MM(pa.v, Vf[cg], acc[cg]);                                   \
} while (0)

    if (kmax_w >= 0) {
        bf16x8s KA[8], KB[8];
        LOADK(KA, 0);
        int kb = 0;
        for (;;) {
            STEP(KA, KB, kb); kb += 32; if (kb > kmax_w) break;
            STEP(KB, KA, kb); kb += 32; if (kb > kmax_w) break;
        }
    }
#undef STEP
#undef LOADK

    // ---- epilogue: C rows = q (reg axis), cols = d (lane axis) ----
    const float linv = 1.0f / l_r;
    float iv[4];
    bool valid[4];
#pragma unroll
    for (int r = 0; r < 4; ++r) {
        const int row = g * 4 + r;
        iv[r] = __shfl(linv, row, 16);
        valid[r] = (qr + row) < len;
    }
    const float invS = 1.0f / (float)S_;
#pragma unroll
    for (int cg = 0; cg < 16; ++cg) {
        const int d = slice * 256 + cg * 16 + c16;
        const float vsv = vsumf[(size_t)b * D_ + d] * invS;
#pragma unroll
        for (int r = 0; r < 4; ++r) {
            const int rowg = qr + g * 4 + r;
            const float val = valid[r] ? acc[cg][r] * iv[r] : vsv;
            out[((size_t)(b * S_ + rowg)) * D_ + d] = val;
        }
    }
}

// ---------------------------------------------------------------------------
extern "C" void kernel_launch(void* const* d_in, const int* in_sizes, int n_in,
                              void* d_out, int out_size, void* d_ws, size_t ws_size,
                              hipStream_t stream) {
    const float*   x    = (const float*)d_in[0];
    const uint8_t* mask = (const uint8_t*)d_in[1];
    const float*   Wq   = (const float*)d_in[2];
    const float*   bq   = (const float*)d_in[3];
    const float*   Wk   = (const float*)d_in[4];
    const float*   bk   = (const float*)d_in[5];
    const float*   Wv   = (const float*)d_in[6];
    const float*   bv   = (const float*)d_in[7];
    float* out = (float*)d_out;

    // workspace (u16 planes), total ~40.4 MB
    u16* u = (u16*)d_ws;
    u16* x_bf = u;                    u += (size_t)8192 * 1024;
    u16* wqt  = u;                    u += (size_t)128 * 1024;
    u16* wkt  = u;                    u += (size_t)128 * 1024;
    u16* wvt  = u;                    u += (size_t)1024 * 1024;
    u16* qb   = u;                    u += (size_t)8192 * 128;
    u16* kbuf = u;                    u += (size_t)8192 * 128;
    u16* vt   = u;                    u += (size_t)B_ * 1024 * 2048;
    float* vsumf = (float*)u;
    int* lengths = (int*)(vsumf + B_ * D_);

    const float SCALE = 0.08838834764831845f;  // 1/sqrt(128)

    lengths_kernel<<<dim3(B_), dim3(256), 0, stream>>>(mask, lengths);
    tobf16_kernel<<<dim3(8192), dim3(256), 0, stream>>>(x, x_bf);
    transpose_tobf16_kernel<<<dim3(4, 32), dim3(256), 0, stream>>>(Wq, wqt, 1024, 128);
    transpose_tobf16_kernel<<<dim3(4, 32), dim3(256), 0, stream>>>(Wk, wkt, 1024, 128);
    transpose_tobf16_kernel<<<dim3(32, 32), dim3(256), 0, stream>>>(Wv, wvt, 1024, 1024);

    // q = (x@Wq + bq)*scale ; k = x@Wk + bk    ([8192][128] bf16)
    gemm_nt<64, 64, 32, 32><<<dim3(2, 128, 1), dim3(256), 0, stream>>>(
        x_bf, wqt, bq, nullptr, SCALE, qb, 128, 1024, 0, 0);
    gemm_nt<64, 64, 32, 32><<<dim3(2, 128, 1), dim3(256), 0, stream>>>(
        x_bf, wkt, bk, nullptr, 1.0f, kbuf, 128, 1024, 0, 0);
    // VT[b] = Wv^T @ x[b]^T + bv[d]   ([1024 d][2048 tok] bf16, per batch)
    gemm_nt<128, 128, 64, 64><<<dim3(16, 8, B_), dim3(256), 0, stream>>>(
        wvt, x_bf, nullptr, bv, 1.0f, vt, 2048, 1024,
        (size_t)2048 * 1024, (size_t)1024 * 2048);

    vsum_rows_kernel<<<dim3(B_ * D_), dim3(64), 0, stream>>>(vt, vsumf);

    flash_mfma<<<dim3(S_ / 64, B_, 4), dim3(256), 0, stream>>>(
        qb, kbuf, vt, vsumf, lengths, out);
}